// Round 4
// baseline (149.665 us; speedup 1.0000x reference)
//
#include <hip/hip_runtime.h>

#define Bn 4
#define Nn 2048
#define NBn 10
#define BN (Bn*Nn)
#define TM 32
#define BIGM 1e32f

// ws layout in float (4-byte) units
#define OFF_PRED 0
#define OFF_GT   (BN*16)
#define OFF_SYM  (2*BN*16)
#define OFF_PN2  (3*BN*16)
#define OFF_GN2  (OFF_PN2 + BN)
#define OFF_SN2  (OFF_GN2 + BN)
#define OFF_BEST (OFF_SN2 + BN)      // uint32 per (b,n)
#define OFF_PK   (OFF_BEST + BN)     // u64 per (b,n): (distbits<<32)|(mat<<11)|idx
#define OFF_PART (OFF_PK + 2*BN)     // 32 blocks x 8 floats: 0=dir 1=app 2=off 3=pos 4=bce

__device__ inline float sp_(float x) {            // jax.nn.softplus, stable form
  return fmaxf(x, 0.0f) + log1pf(expf(-fabsf(x)));
}

__device__ inline float dot16_(const float4&a0,const float4&a1,const float4&a2,const float4&a3,
                               const float4&b0,const float4&b1,const float4&b2,const float4&b3){
  float s0 = fmaf(a0.w,b0.w, fmaf(a0.z,b0.z, fmaf(a0.y,b0.y, a0.x*b0.x)));
  float s1 = fmaf(a1.w,b1.w, fmaf(a1.z,b1.z, fmaf(a1.y,b1.y, a1.x*b1.x)));
  float s2 = fmaf(a2.w,b2.w, fmaf(a2.z,b2.z, fmaf(a2.y,b2.y, a2.x*b2.x)));
  float s3 = fmaf(a3.w,b3.w, fmaf(a3.z,b3.z, fmaf(a3.y,b3.y, a3.x*b3.x)));
  return (s0+s1)+(s2+s3);
}

__device__ inline float blockSum_(float v, float* red) {
  #pragma unroll
  for (int o = 32; o > 0; o >>= 1) v += __shfl_down(v, o, 64);
  __syncthreads();
  if ((threadIdx.x & 63) == 0) red[threadIdx.x >> 6] = v;
  __syncthreads();
  return red[0] + red[1] + red[2] + red[3];
}

// ---------- prep: frames, control points, norms, min-state init, cheap per-point
// loss partials. grid (BN/256) = 32, block 256.
__global__ __launch_bounds__(256) void k_prep(
    const float* __restrict__ gdir, const float* __restrict__ adirp,
    const float* __restrict__ goff, const float* __restrict__ ppts,
    const float* __restrict__ bsh,
    const float* __restrict__ dlab, const float* __restrict__ olab,
    const float* __restrict__ succ, const float* __restrict__ alab,
    const float* __restrict__ binv, const float* __restrict__ binw,
    const float* __restrict__ cpts, const float* __restrict__ scpts,
    float* __restrict__ ws)
{
  __shared__ float red[4];
  const int pb = blockIdx.x;
  const int idx = pb * 256 + threadIdx.x;

  const float gd0=gdir[idx*3+0],  gd1=gdir[idx*3+1],  gd2=gdir[idx*3+2];
  const float ad0=adirp[idx*3+0], ad1=adirp[idx*3+1], ad2=adirp[idx*3+2];
  const float dl0=dlab[idx*3+0],  dl1=dlab[idx*3+1],  dl2=dlab[idx*3+2];
  const float al0=alab[idx*3+0],  al1=alab[idx*3+1],  al2=alab[idx*3+2];
  const float pt0=ppts[idx*3+0],  pt1=ppts[idx*3+1],  pt2=ppts[idx*3+2];
  const float sc = succ[idx];

  // argmax (first occurrence, matches jnp.argmax)
  float bv = goff[idx*NBn]; int ap = 0;
  #pragma unroll
  for (int k = 1; k < NBn; k++) { float v = goff[idx*NBn+k]; if (v > bv) { bv = v; ap = k; } }
  float bg = olab[idx*NBn]; int ag = 0;
  #pragma unroll
  for (int k = 1; k < NBn; k++) { float v = olab[idx*NBn+k]; if (v > bg) { bg = v; ag = k; } }
  const float tp = binv[ap] * 0.5f;
  const float tg = binv[ag] * 0.5f;

  // frames: cross = cross(approach, base); t = pt + 0.5*thickness*base
  const float cp0 = ad1*gd2 - ad2*gd1, cp1 = ad2*gd0 - ad0*gd2, cp2 = ad0*gd1 - ad1*gd0;
  const float cg0 = al1*dl2 - al2*dl1, cg1 = al2*dl0 - al0*dl2, cg2 = al0*dl1 - al1*dl0;
  const float tpx = pt0 + tp*gd0, tpy = pt1 + tp*gd1, tpz = pt2 + tp*gd2;
  const float tgx = pt0 + tg*dl0, tgy = pt1 + tg*dl1, tgz = pt2 + tg*dl2;

  float pcp[15], gcp[15], hcp[15];
  float pn2 = 0.f, gn2 = 0.f, sn2 = 0.f;
  #pragma unroll
  for (int p = 0; p < 5; p++) {
    const float cx = cpts[p*3], cy = cpts[p*3+1], cz = cpts[p*3+2];
    const float sx = scpts[p*3], sy = scpts[p*3+1], sz = scpts[p*3+2];
    float x, y, z;
    x = gd0*cx + cp0*cy + ad0*cz + tpx;
    y = gd1*cx + cp1*cy + ad1*cz + tpy;
    z = gd2*cx + cp2*cy + ad2*cz + tpz;
    pcp[p*3+0]=x; pcp[p*3+1]=y; pcp[p*3+2]=z;
    pn2 = fmaf(x,x, fmaf(y,y, fmaf(z,z, pn2)));
    x = dl0*cx + cg0*cy + al0*cz + tgx;
    y = dl1*cx + cg1*cy + al1*cz + tgy;
    z = dl2*cx + cg2*cy + al2*cz + tgz;
    gcp[p*3+0]=x; gcp[p*3+1]=y; gcp[p*3+2]=z;
    gn2 = fmaf(x,x, fmaf(y,y, fmaf(z,z, gn2)));
    x = dl0*sx + cg0*sy + al0*sz + tgx;
    y = dl1*sx + cg1*sy + al1*sz + tgy;
    z = dl2*sx + cg2*sy + al2*sz + tgz;
    hcp[p*3+0]=x; hcp[p*3+1]=y; hcp[p*3+2]=z;
    sn2 = fmaf(x,x, fmaf(y,y, fmaf(z,z, sn2)));
  }

  float4* pd = (float4*)(ws + OFF_PRED) + (size_t)idx*4;
  pd[0]=make_float4(pcp[0],pcp[1],pcp[2],pcp[3]);
  pd[1]=make_float4(pcp[4],pcp[5],pcp[6],pcp[7]);
  pd[2]=make_float4(pcp[8],pcp[9],pcp[10],pcp[11]);
  pd[3]=make_float4(pcp[12],pcp[13],pcp[14],0.f);
  float4* gdst = (float4*)(ws + OFF_GT) + (size_t)idx*4;
  gdst[0]=make_float4(gcp[0],gcp[1],gcp[2],gcp[3]);
  gdst[1]=make_float4(gcp[4],gcp[5],gcp[6],gcp[7]);
  gdst[2]=make_float4(gcp[8],gcp[9],gcp[10],gcp[11]);
  gdst[3]=make_float4(gcp[12],gcp[13],gcp[14],0.f);
  float4* sdst = (float4*)(ws + OFF_SYM) + (size_t)idx*4;
  sdst[0]=make_float4(hcp[0],hcp[1],hcp[2],hcp[3]);
  sdst[1]=make_float4(hcp[4],hcp[5],hcp[6],hcp[7]);
  sdst[2]=make_float4(hcp[8],hcp[9],hcp[10],hcp[11]);
  sdst[3]=make_float4(hcp[12],hcp[13],hcp[14],0.f);
  ws[OFF_PN2+idx] = pn2; ws[OFF_GN2+idx] = gn2; ws[OFF_SN2+idx] = sn2;

  // per-idx min-state init (k_pair runs strictly after)
  ((unsigned*)ws)[OFF_BEST + idx] = 0x7F800000u;   // +inf
  ((unsigned long long*)(ws + OFF_PK))[idx] = ~0ull;

  // ---- cheap per-point losses -> per-block partials ----
  const float cosd = 1.f - (dl0*gd0 + dl1*gd1 + dl2*gd2);
  const float proj = gd0*al0 + gd1*al1 + gd2*al2;
  const float o0 = al0 - proj*gd0, o1 = al1 - proj*gd1, o2 = al2 - proj*gd2;
  const float on = sqrtf(o0*o0 + o1*o1 + o2*o2);
  const float inv = 1.f / fmaxf(on, 1e-12f);
  const float cosa = 1.f - inv*(o0*ad0 + o1*ad1 + o2*ad2);

  float offv = 0.f;
  #pragma unroll
  for (int k = 0; k < NBn; k++) {
    const float x = goff[idx*NBn+k], lab = olab[idx*NBn+k];
    const float bce = lab * sp_(-x) + (1.f - lab) * sp_(x);
    offv = fmaf(binw[k], bce, offv);
  }
  offv *= (1.0f / NBn);
  const float sb = bsh[idx];
  const float sbce = sc * sp_(-sb) + (1.f - sc) * sp_(sb);

  float* part = ws + OFF_PART + (size_t)pb*8;
  float t;
  t = blockSum_(cosd*sc, red); if (threadIdx.x == 0) part[0] = t;
  t = blockSum_(cosa*sc, red); if (threadIdx.x == 0) part[1] = t;
  t = blockSum_(offv*sc, red); if (threadIdx.x == 0) part[2] = t;
  t = blockSum_(sc, red);      if (threadIdx.x == 0) part[3] = t;
  t = blockSum_(sbce, red);    if (threadIdx.x == 0) part[4] = t;
}

// ---------- fused pairwise kernel. grid (Nn/TM, Nn/512, Bn) = (64,4,4), block 256.
// Each thread owns 2 n-rows. Phase A: forward row-min (mask folded into norms).
// Phase B: backward min+argmin, both matrices combined into one packed u64.
__global__ __launch_bounds__(256, 4) void k_pair(const float* __restrict__ succ,
                                                 float* __restrict__ ws) {
  __shared__ float gts[TM*16], sys[TM*16], prs[TM*16];
  __shared__ float gb2[TM], sb2[TM], pb2[TM];
  const int mt = blockIdx.x, nt = blockIdx.y, b = blockIdx.z;
  const int tid = threadIdx.x;
  const int mbase = mt*TM;
  {
    const float2* gsrc = (const float2*)(ws + OFF_GT  + (size_t)(b*Nn + mbase)*16);
    const float2* ssrc = (const float2*)(ws + OFF_SYM + (size_t)(b*Nn + mbase)*16);
    const float2* psrc = (const float2*)(ws + OFF_PRED+ (size_t)(b*Nn + mbase)*16);
    ((float2*)gts)[tid] = gsrc[tid];            // 32 rows x 16 floats = 256 float2
    ((float2*)sys)[tid] = ssrc[tid];
    ((float2*)prs)[tid] = psrc[tid];
    if (tid < TM) {
      const int mrow = b*Nn + mbase + tid;
      const float bias = (succ[mrow] != 0.f) ? 0.f : BIGM;
      gb2[tid] = ws[OFF_GN2 + mrow] + bias;
      sb2[tid] = ws[OFF_SN2 + mrow] + bias;
      pb2[tid] = ws[OFF_PN2 + mrow];
    }
  }
  __syncthreads();

  const int nrow0 = b*Nn + nt*512 + tid;
  const int nrow1 = nrow0 + 256;

  // ---- phase A ----
  {
    const float4* pa0 = (const float4*)(ws + OFF_PRED) + (size_t)nrow0*4;
    const float4 a00=pa0[0], a01=pa0[1], a02=pa0[2], a03=pa0[3];
    const float4* pa1 = (const float4*)(ws + OFF_PRED) + (size_t)nrow1*4;
    const float4 a10=pa1[0], a11=pa1[1], a12=pa1[2], a13=pa1[3];
    const float an20 = ws[OFF_PN2+nrow0], an21 = ws[OFF_PN2+nrow1];
    float best0 = 1e38f, best1 = 1e38f;
    const float4* G = (const float4*)gts;
    const float4* S = (const float4*)sys;
    for (int m = 0; m < TM; m++) {
      const float4 g0=G[m*4+0], g1=G[m*4+1], g2=G[m*4+2], g3=G[m*4+3];
      const float4 s0=S[m*4+0], s1=S[m*4+1], s2=S[m*4+2], s3=S[m*4+3];
      const float gb = gb2[m], sb = sb2[m];
      float d;
      d = fmaxf(fmaf(-2.f, dot16_(a00,a01,a02,a03,g0,g1,g2,g3), an20+gb), 0.f);
      best0 = fminf(best0, d);
      d = fmaxf(fmaf(-2.f, dot16_(a00,a01,a02,a03,s0,s1,s2,s3), an20+sb), 0.f);
      best0 = fminf(best0, d);
      d = fmaxf(fmaf(-2.f, dot16_(a10,a11,a12,a13,g0,g1,g2,g3), an21+gb), 0.f);
      best1 = fminf(best1, d);
      d = fmaxf(fmaf(-2.f, dot16_(a10,a11,a12,a13,s0,s1,s2,s3), an21+sb), 0.f);
      best1 = fminf(best1, d);
    }
    atomicMin((unsigned*)ws + OFF_BEST + nrow0, __float_as_uint(best0));
    atomicMin((unsigned*)ws + OFF_BEST + nrow1, __float_as_uint(best1));
  }

  // ---- phase B ----
  {
    const float4* gp0 = (const float4*)(ws + OFF_GT)  + (size_t)nrow0*4;
    const float4 g00=gp0[0], g01=gp0[1], g02=gp0[2], g03=gp0[3];
    const float4* sp0 = (const float4*)(ws + OFF_SYM) + (size_t)nrow0*4;
    const float4 s00=sp0[0], s01=sp0[1], s02=sp0[2], s03=sp0[3];
    const float4* gp1 = (const float4*)(ws + OFF_GT)  + (size_t)nrow1*4;
    const float4 g10=gp1[0], g11=gp1[1], g12=gp1[2], g13=gp1[3];
    const float4* sp1 = (const float4*)(ws + OFF_SYM) + (size_t)nrow1*4;
    const float4 s10=sp1[0], s11=sp1[1], s12=sp1[2], s13=sp1[3];
    const float gn20 = ws[OFF_GN2+nrow0], sn20 = ws[OFF_SN2+nrow0];
    const float gn21 = ws[OFF_GN2+nrow1], sn21 = ws[OFF_SN2+nrow1];

    float bd10=1e38f, bd20=1e38f, bd11=1e38f, bd21=1e38f;
    int   bi10=0,     bi20=0,     bi11=0,     bi21=0;
    const float4* P = (const float4*)prs;
    for (int m = 0; m < TM; m++) {
      const float4 p0=P[m*4+0], p1=P[m*4+1], p2=P[m*4+2], p3=P[m*4+3];
      const float pb = pb2[m];
      float d;
      d = fmaxf(fmaf(-2.f, dot16_(g00,g01,g02,g03,p0,p1,p2,p3), gn20+pb), 0.f);
      if (d < bd10) { bd10 = d; bi10 = m; }
      d = fmaxf(fmaf(-2.f, dot16_(s00,s01,s02,s03,p0,p1,p2,p3), sn20+pb), 0.f);
      if (d < bd20) { bd20 = d; bi20 = m; }
      d = fmaxf(fmaf(-2.f, dot16_(g10,g11,g12,g13,p0,p1,p2,p3), gn21+pb), 0.f);
      if (d < bd11) { bd11 = d; bi11 = m; }
      d = fmaxf(fmaf(-2.f, dot16_(s10,s11,s12,s13,p0,p1,p2,p3), sn21+pb), 0.f);
      if (d < bd21) { bd21 = d; bi21 = m; }
    }
    // pack: (distbits<<32) | (mat<<11) | global_idx.  u64 min == lexicographic
    // (d, mat, idx): d-tie -> mat0 (= reference's i1-on-tie), then first occurrence.
    unsigned long long c1, c2, q;
    c1 = ((unsigned long long)__float_as_uint(bd10) << 32) | (unsigned)(mbase + bi10);
    c2 = ((unsigned long long)__float_as_uint(bd20) << 32) | (unsigned)(2048 + mbase + bi20);
    q = (c1 < c2) ? c1 : c2;
    atomicMin((unsigned long long*)(ws + OFF_PK) + nrow0, q);
    c1 = ((unsigned long long)__float_as_uint(bd11) << 32) | (unsigned)(mbase + bi11);
    c2 = ((unsigned long long)__float_as_uint(bd21) << 32) | (unsigned)(2048 + mbase + bi21);
    q = (c1 < c2) ? c1 : c2;
    atomicMin((unsigned long long*)(ws + OFF_PK) + nrow1, q);
  }
}

// ---------- tail: adds/g2p over all points + final combine. 1 block x 1024.
__global__ __launch_bounds__(1024) void k_tail(const float* __restrict__ bsp,
                                               const float* __restrict__ succ,
                                               const float* __restrict__ ws,
                                               float* __restrict__ out) {
  __shared__ float wadds[16], wg2p[16];
  __shared__ float ldsA[4], ldsP[4], ldsG[4];
  const int t = threadIdx.x;
  const int b = t >> 8;                       // 256 threads (8 idx each) per batch
  float adds = 0.f, g2p = 0.f;
  #pragma unroll
  for (int i = 0; i < 8; i++) {
    const int idx = t*8 + i;
    const float best = __uint_as_float(((const unsigned*)ws)[OFF_BEST + idx]);
    if (best < 1e30f) adds += bsp[idx] * sqrtf(best);   // else: no positives -> gate 0
    const unsigned long long q = ((const unsigned long long*)(ws + OFF_PK))[idx];
    const float d = __uint_as_float((unsigned)(q >> 32));
    const int  id = (int)(q & 2047ull);
    g2p += bsp[b*Nn + id] * d * succ[idx];
  }
  #pragma unroll
  for (int o = 32; o > 0; o >>= 1) { adds += __shfl_down(adds, o, 64); g2p += __shfl_down(g2p, o, 64); }
  if ((t & 63) == 0) { wadds[t>>6] = adds; wg2p[t>>6] = g2p; }
  __syncthreads();
  if (t >= 64) return;

  float v0=0.f, v1=0.f, v2=0.f, v3=0.f, v4=0.f;
  if (t < 32) {
    const float* part = ws + OFF_PART + (size_t)t*8;
    v0=part[0]; v1=part[1]; v2=part[2]; v3=part[3]; v4=part[4];
  }
  #pragma unroll
  for (int o = 1; o < 8; o <<= 1) {          // per-b sums (b = t>>3) at lanes 0..31
    v0 += __shfl_xor(v0,o,64); v1 += __shfl_xor(v1,o,64);
    v2 += __shfl_xor(v2,o,64); v3 += __shfl_xor(v3,o,64);
    v4 += __shfl_xor(v4,o,64);
  }
  float bce = v4;
  bce += __shfl_xor(bce,8,64); bce += __shfl_xor(bce,16,64);   // global bce (lanes<32)
  float ga = (t<16) ? wg2p[t] : 0.f;                            // wave w -> b = w>>2
  ga += __shfl_xor(ga,1,64); ga += __shfl_xor(ga,2,64);         // per-b (b = t>>2)
  float aa = (t<16) ? wadds[t] : 0.f;
  aa += __shfl_xor(aa,1,64); aa += __shfl_xor(aa,2,64);
  aa += __shfl_xor(aa,4,64); aa += __shfl_xor(aa,8,64);         // global adds
  if (t<32 && (t&7)==0) { ldsA[t>>3] = v0+v1+v2; ldsP[t>>3] = v3; }
  if (t<16 && (t&3)==0) { ldsG[t>>2] = ga; }
  __threadfence_block();
  float vb = 0.f;
  if (t < 4) vb = (ldsA[t] + ldsG[t]) / fmaxf(ldsP[t], 1.f);
  vb += __shfl_xor(vb,1,64); vb += __shfl_xor(vb,2,64);
  if (t == 0)
    out[0] = vb * 0.25f + bce * (1.f/BN) + 10.f * aa * (1.f/BN);
}

extern "C" void kernel_launch(void* const* d_in, const int* in_sizes, int n_in,
                              void* d_out, int out_size, void* d_ws, size_t ws_size,
                              hipStream_t stream) {
  const float* gdir  = (const float*)d_in[0];
  const float* adirp = (const float*)d_in[1];
  const float* goff  = (const float*)d_in[2];
  const float* ppts  = (const float*)d_in[3];
  const float* bsp   = (const float*)d_in[4];
  const float* bsh   = (const float*)d_in[5];
  const float* dlab  = (const float*)d_in[6];
  const float* olab  = (const float*)d_in[7];
  const float* succ  = (const float*)d_in[8];
  const float* alab  = (const float*)d_in[9];
  const float* binv  = (const float*)d_in[10];
  const float* binw  = (const float*)d_in[11];
  const float* cpts  = (const float*)d_in[12];
  const float* scpts = (const float*)d_in[13];
  float* ws  = (float*)d_ws;
  float* out = (float*)d_out;

  k_prep<<<dim3(BN/256), dim3(256), 0, stream>>>(gdir, adirp, goff, ppts, bsh,
                                                 dlab, olab, succ, alab,
                                                 binv, binw, cpts, scpts, ws);
  k_pair<<<dim3(Nn/TM, Nn/512, Bn), dim3(256), 0, stream>>>(succ, ws);
  k_tail<<<1, 1024, 0, stream>>>(bsp, succ, ws, out);
}

// Round 5
// 139.154 us; speedup vs baseline: 1.0755x; 1.0755x over previous
//
#include <hip/hip_runtime.h>

#define Bn 4
#define Nn 2048
#define NBn 10
#define BN (Bn*Nn)
#define TCOLS 128     // gt columns per block (2 per lane, shared by all 4 waves)
#define NCH 64        // pred rows per block (16 per wave)
#define BIGM 1e32f

// ws layout in float (4-byte) units
#define OFF_PRED 0
#define OFF_GT   (BN*16)
#define OFF_SYM  (2*BN*16)
#define OFF_PN2  (3*BN*16)
#define OFF_GN2  (OFF_PN2 + BN)
#define OFF_SN2  (OFF_GN2 + BN)
#define OFF_BEST (OFF_SN2 + BN)      // u32 per (b,n): forward min dist (fp32 bits)
#define OFF_PK   (OFF_BEST + BN)     // u32 per (b,m): (dist&0xFFFFF000)|(mat<<11)|n
#define OFF_PART (OFF_PK + BN)       // 32 records x 8 floats: 0=dir 1=app 2=off 3=pos 4=bce 5=adds 6=g2p

__device__ inline float sp_(float x) {            // jax.nn.softplus, stable form
  return fmaxf(x, 0.0f) + log1pf(expf(-fabsf(x)));
}

// dot of wave-uniform pred row p[15] (16th elem is 0 on both sides) with lane's column quads
__device__ inline float dotp_(const float* p, const float4&b0,const float4&b1,const float4&b2,const float4&b3){
  float s0 = fmaf(p[3], b0.w, fmaf(p[2], b0.z, fmaf(p[1], b0.y, p[0]*b0.x)));
  float s1 = fmaf(p[7], b1.w, fmaf(p[6], b1.z, fmaf(p[5], b1.y, p[4]*b1.x)));
  float s2 = fmaf(p[11],b2.w, fmaf(p[10],b2.z, fmaf(p[9], b2.y, p[8]*b2.x)));
  float s3 = fmaf(p[14],b3.z, fmaf(p[13],b3.y, p[12]*b3.x));
  return (s0+s1)+(s2+s3);
}

__device__ inline float blockSum_(float v, float* red) {
  #pragma unroll
  for (int o = 32; o > 0; o >>= 1) v += __shfl_down(v, o, 64);
  __syncthreads();
  if ((threadIdx.x & 63) == 0) red[threadIdx.x >> 6] = v;
  __syncthreads();
  return red[0] + red[1] + red[2] + red[3];
}

// ---------- prep: frames, control points, norms, min-state init, cheap per-point
// loss partials. grid (BN/256) = 32, block 256.
__global__ __launch_bounds__(256) void k_prep(
    const float* __restrict__ gdir, const float* __restrict__ adirp,
    const float* __restrict__ goff, const float* __restrict__ ppts,
    const float* __restrict__ bsh,
    const float* __restrict__ dlab, const float* __restrict__ olab,
    const float* __restrict__ succ, const float* __restrict__ alab,
    const float* __restrict__ binv, const float* __restrict__ binw,
    const float* __restrict__ cpts, const float* __restrict__ scpts,
    float* __restrict__ ws)
{
  __shared__ float red[4];
  const int pb = blockIdx.x;
  const int idx = pb * 256 + threadIdx.x;

  const float gd0=gdir[idx*3+0],  gd1=gdir[idx*3+1],  gd2=gdir[idx*3+2];
  const float ad0=adirp[idx*3+0], ad1=adirp[idx*3+1], ad2=adirp[idx*3+2];
  const float dl0=dlab[idx*3+0],  dl1=dlab[idx*3+1],  dl2=dlab[idx*3+2];
  const float al0=alab[idx*3+0],  al1=alab[idx*3+1],  al2=alab[idx*3+2];
  const float pt0=ppts[idx*3+0],  pt1=ppts[idx*3+1],  pt2=ppts[idx*3+2];
  const float sc = succ[idx];

  // argmax (first occurrence, matches jnp.argmax)
  float bv = goff[idx*NBn]; int ap = 0;
  #pragma unroll
  for (int k = 1; k < NBn; k++) { float v = goff[idx*NBn+k]; if (v > bv) { bv = v; ap = k; } }
  float bg = olab[idx*NBn]; int ag = 0;
  #pragma unroll
  for (int k = 1; k < NBn; k++) { float v = olab[idx*NBn+k]; if (v > bg) { bg = v; ag = k; } }
  const float tp = binv[ap] * 0.5f;
  const float tg = binv[ag] * 0.5f;

  // frames: cross = cross(approach, base); t = pt + 0.5*thickness*base
  const float cp0 = ad1*gd2 - ad2*gd1, cp1 = ad2*gd0 - ad0*gd2, cp2 = ad0*gd1 - ad1*gd0;
  const float cg0 = al1*dl2 - al2*dl1, cg1 = al2*dl0 - al0*dl2, cg2 = al0*dl1 - al1*dl0;
  const float tpx = pt0 + tp*gd0, tpy = pt1 + tp*gd1, tpz = pt2 + tp*gd2;
  const float tgx = pt0 + tg*dl0, tgy = pt1 + tg*dl1, tgz = pt2 + tg*dl2;

  float pcp[15], gcp[15], hcp[15];
  float pn2 = 0.f, gn2 = 0.f, sn2 = 0.f;
  #pragma unroll
  for (int p = 0; p < 5; p++) {
    const float cx = cpts[p*3], cy = cpts[p*3+1], cz = cpts[p*3+2];
    const float sx = scpts[p*3], sy = scpts[p*3+1], sz = scpts[p*3+2];
    float x, y, z;
    x = gd0*cx + cp0*cy + ad0*cz + tpx;
    y = gd1*cx + cp1*cy + ad1*cz + tpy;
    z = gd2*cx + cp2*cy + ad2*cz + tpz;
    pcp[p*3+0]=x; pcp[p*3+1]=y; pcp[p*3+2]=z;
    pn2 = fmaf(x,x, fmaf(y,y, fmaf(z,z, pn2)));
    x = dl0*cx + cg0*cy + al0*cz + tgx;
    y = dl1*cx + cg1*cy + al1*cz + tgy;
    z = dl2*cx + cg2*cy + al2*cz + tgz;
    gcp[p*3+0]=x; gcp[p*3+1]=y; gcp[p*3+2]=z;
    gn2 = fmaf(x,x, fmaf(y,y, fmaf(z,z, gn2)));
    x = dl0*sx + cg0*sy + al0*sz + tgx;
    y = dl1*sx + cg1*sy + al1*sz + tgy;
    z = dl2*sx + cg2*sy + al2*sz + tgz;
    hcp[p*3+0]=x; hcp[p*3+1]=y; hcp[p*3+2]=z;
    sn2 = fmaf(x,x, fmaf(y,y, fmaf(z,z, sn2)));
  }

  float4* pd = (float4*)(ws + OFF_PRED) + (size_t)idx*4;
  pd[0]=make_float4(pcp[0],pcp[1],pcp[2],pcp[3]);
  pd[1]=make_float4(pcp[4],pcp[5],pcp[6],pcp[7]);
  pd[2]=make_float4(pcp[8],pcp[9],pcp[10],pcp[11]);
  pd[3]=make_float4(pcp[12],pcp[13],pcp[14],0.f);
  float4* gdst = (float4*)(ws + OFF_GT) + (size_t)idx*4;
  gdst[0]=make_float4(gcp[0],gcp[1],gcp[2],gcp[3]);
  gdst[1]=make_float4(gcp[4],gcp[5],gcp[6],gcp[7]);
  gdst[2]=make_float4(gcp[8],gcp[9],gcp[10],gcp[11]);
  gdst[3]=make_float4(gcp[12],gcp[13],gcp[14],0.f);
  float4* sdst = (float4*)(ws + OFF_SYM) + (size_t)idx*4;
  sdst[0]=make_float4(hcp[0],hcp[1],hcp[2],hcp[3]);
  sdst[1]=make_float4(hcp[4],hcp[5],hcp[6],hcp[7]);
  sdst[2]=make_float4(hcp[8],hcp[9],hcp[10],hcp[11]);
  sdst[3]=make_float4(hcp[12],hcp[13],hcp[14],0.f);
  ws[OFF_PN2+idx] = pn2; ws[OFF_GN2+idx] = gn2; ws[OFF_SN2+idx] = sn2;

  // per-idx min-state init (k_pair runs strictly after)
  ((unsigned*)ws)[OFF_BEST + idx] = 0x7F800000u;   // +inf
  ((unsigned*)ws)[OFF_PK   + idx] = 0xFFFFFFFFu;

  // ---- cheap per-point losses -> per-block partials ----
  const float cosd = 1.f - (dl0*gd0 + dl1*gd1 + dl2*gd2);
  const float proj = gd0*al0 + gd1*al1 + gd2*al2;
  const float o0 = al0 - proj*gd0, o1 = al1 - proj*gd1, o2 = al2 - proj*gd2;
  const float on = sqrtf(o0*o0 + o1*o1 + o2*o2);
  const float inv = 1.f / fmaxf(on, 1e-12f);
  const float cosa = 1.f - inv*(o0*ad0 + o1*ad1 + o2*ad2);

  float offv = 0.f;
  #pragma unroll
  for (int k = 0; k < NBn; k++) {
    const float x = goff[idx*NBn+k], lab = olab[idx*NBn+k];
    const float bce = lab * sp_(-x) + (1.f - lab) * sp_(x);
    offv = fmaf(binw[k], bce, offv);
  }
  offv *= (1.0f / NBn);
  const float sb = bsh[idx];
  const float sbce = sc * sp_(-sb) + (1.f - sc) * sp_(sb);

  float* part = ws + OFF_PART + (size_t)pb*8;
  float t;
  t = blockSum_(cosd*sc, red); if (threadIdx.x == 0) part[0] = t;
  t = blockSum_(cosa*sc, red); if (threadIdx.x == 0) part[1] = t;
  t = blockSum_(offv*sc, red); if (threadIdx.x == 0) part[2] = t;
  t = blockSum_(sc, red);      if (threadIdx.x == 0) part[3] = t;
  t = blockSum_(sbce, red);    if (threadIdx.x == 0) part[4] = t;
}

// ---------- single-pass pairwise kernel. grid (Nn/TCOLS, Nn/NCH, Bn) = (16,32,4), block 256.
// Each lane owns 2 gt columns (gt+sym fragments in registers). All 4 waves cover the
// SAME 128 columns; each wave iterates a disjoint 16-row pred slice (wave-uniform n
// -> broadcast/scalar loads, no LDS staging). Each D1/D2 value is computed ONCE:
//   forward (pred-side): mask-biased min across lanes via shfl butterfly -> atomicMin BEST[n]
//   backward (gt-side):  thread-local packed-key min -> LDS merge -> atomicMin PK[col]
__global__ __launch_bounds__(256) void k_pair(const float* __restrict__ succ,
                                              float* __restrict__ ws) {
  __shared__ unsigned bkey[TCOLS];
  const int tile = blockIdx.x * TCOLS, b = blockIdx.z;
  const int bN = b * Nn;
  const int tid = threadIdx.x;
  const int lane = tid & 63;
  const int wid = __builtin_amdgcn_readfirstlane(tid >> 6);

  if (tid < TCOLS) bkey[tid] = 0xFFFFFFFFu;

  // lane's two columns
  const int r0 = bN + tile + lane;
  const int r1 = r0 + 64;
  const float4* G = (const float4*)(ws + OFF_GT);
  const float4* S = (const float4*)(ws + OFF_SYM);
  const float4 g00=G[(size_t)r0*4+0], g01=G[(size_t)r0*4+1], g02=G[(size_t)r0*4+2], g03=G[(size_t)r0*4+3];
  const float4 g10=G[(size_t)r1*4+0], g11=G[(size_t)r1*4+1], g12=G[(size_t)r1*4+2], g13=G[(size_t)r1*4+3];
  const float4 s00=S[(size_t)r0*4+0], s01=S[(size_t)r0*4+1], s02=S[(size_t)r0*4+2], s03=S[(size_t)r0*4+3];
  const float4 s10=S[(size_t)r1*4+0], s11=S[(size_t)r1*4+1], s12=S[(size_t)r1*4+2], s13=S[(size_t)r1*4+3];
  const float gn0 = ws[OFF_GN2+r0], gn1 = ws[OFF_GN2+r1];
  const float sn0 = ws[OFF_SN2+r0], sn1 = ws[OFF_SN2+r1];
  const float bias0 = (succ[r0] != 0.f) ? 0.f : BIGM;
  const float bias1 = (succ[r1] != 0.f) ? 0.f : BIGM;

  unsigned k0 = 0xFFFFFFFFu, k1 = 0xFFFFFFFFu;
  __syncthreads();

  const int nbase = blockIdx.y * NCH + wid * (NCH/4);
  #pragma unroll 2
  for (int j = 0; j < NCH/4; j++) {
    const int n = nbase + j;                                 // wave-uniform
    const float* pr = ws + OFF_PRED + (size_t)(bN + n)*16;
    float p[15];
    #pragma unroll
    for (int q = 0; q < 15; q++) p[q] = pr[q];
    const float pn2 = ws[OFF_PN2 + bN + n];

    const float d10 = fmaxf(fmaf(-2.f, dotp_(p, g00,g01,g02,g03), pn2 + gn0), 0.f);
    const float d20 = fmaxf(fmaf(-2.f, dotp_(p, s00,s01,s02,s03), pn2 + sn0), 0.f);
    const float d11 = fmaxf(fmaf(-2.f, dotp_(p, g10,g11,g12,g13), pn2 + gn1), 0.f);
    const float d21 = fmaxf(fmaf(-2.f, dotp_(p, s10,s11,s12,s13), pn2 + sn1), 0.f);

    // backward packed keys: (dist&0xFFFFF000)|(mat<<11)|n  — u32 min is
    // lexicographic (d, mat, n): d-tie -> mat0 (= reference i1-on-tie), then first n.
    const unsigned nl = (unsigned)n, nh = (unsigned)n | 0x800u;
    unsigned t0 = (__float_as_uint(d10) & 0xFFFFF000u) | nl;
    unsigned t1 = (__float_as_uint(d20) & 0xFFFFF000u) | nh;
    k0 = min(k0, min(t0, t1));
    t0 = (__float_as_uint(d11) & 0xFFFFF000u) | nl;
    t1 = (__float_as_uint(d21) & 0xFFFFF000u) | nh;
    k1 = min(k1, min(t0, t1));

    // forward: masked min over this wave's 128 columns
    float f = fminf(fminf(d10, d20) + bias0, fminf(d11, d21) + bias1);
    #pragma unroll
    for (int o = 1; o < 64; o <<= 1) f = fminf(f, __shfl_xor(f, o, 64));
    if (lane == 0)
      atomicMin((unsigned*)ws + OFF_BEST + bN + n, __float_as_uint(f));
  }

  // merge the 4 waves' backward keys (same columns, disjoint n) then one global atomic/col
  atomicMin(&bkey[lane], k0);
  atomicMin(&bkey[64 + lane], k1);
  __syncthreads();
  if (tid < TCOLS)
    atomicMin((unsigned*)ws + OFF_PK + bN + tile + tid, bkey[tid]);
}

// ---------- reduce: adds/g2p per-block partials. grid (Nn/256, Bn) = (8,4), block 256.
__global__ __launch_bounds__(256) void k_red(const float* __restrict__ bsp,
                                             const float* __restrict__ succ,
                                             float* __restrict__ ws) {
  __shared__ float red[4];
  const int b = blockIdx.y, nt = blockIdx.x;
  const int idx = b*Nn + nt*256 + threadIdx.x;

  const float best = __uint_as_float(((const unsigned*)ws)[OFF_BEST + idx]);
  const float adds = (best < 1e30f) ? bsp[idx] * sqrtf(best) : 0.f;  // >=1e30 <=> no positives -> gate 0

  const unsigned key = ((const unsigned*)ws)[OFF_PK + idx];
  const float d = __uint_as_float(key & 0xFFFFF000u);
  const int  id = (int)(key & 0x7FFu);
  const float g2p = bsp[b*Nn + id] * d * succ[idx];

  float* part = ws + OFF_PART + (size_t)(b*8 + nt)*8;
  float t;
  t = blockSum_(adds, red); if (threadIdx.x == 0) part[5] = t;
  t = blockSum_(g2p, red);  if (threadIdx.x == 0) part[6] = t;
}

// ---------- finalize: 1 block, 64 threads, wave-only reduction of 32x7 partials
__global__ __launch_bounds__(64) void k_fin(const float* __restrict__ ws, float* __restrict__ out) {
  const int t = threadIdx.x;
  float v[7];
  #pragma unroll
  for (int c = 0; c < 7; c++) v[c] = (t < 32) ? ws[OFF_PART + t*8 + c] : 0.f;
  #pragma unroll
  for (int o = 1; o < 8; o <<= 1) {
    #pragma unroll
    for (int c = 0; c < 7; c++) v[c] += __shfl_xor(v[c], o, 64);
  }
  // each 8-lane group (t<32) now holds per-b sums (b = t>>3)
  const float pos = fmaxf(v[3], 1.f);
  float vb   = (v[0] + v[1] + v[2] + v[6]) / pos;   // dir + app + off + g2p, per-b normalized
  float bce  = v[4];
  float adds = v[5];
  #pragma unroll
  for (int o = 8; o < 32; o <<= 1) {
    vb   += __shfl_xor(vb,   o, 64);
    bce  += __shfl_xor(bce,  o, 64);
    adds += __shfl_xor(adds, o, 64);
  }
  if (t == 0)
    out[0] = vb * 0.25f + bce * (1.f/BN) + 10.f * adds * (1.f/BN);
}

extern "C" void kernel_launch(void* const* d_in, const int* in_sizes, int n_in,
                              void* d_out, int out_size, void* d_ws, size_t ws_size,
                              hipStream_t stream) {
  const float* gdir  = (const float*)d_in[0];
  const float* adirp = (const float*)d_in[1];
  const float* goff  = (const float*)d_in[2];
  const float* ppts  = (const float*)d_in[3];
  const float* bsp   = (const float*)d_in[4];
  const float* bsh   = (const float*)d_in[5];
  const float* dlab  = (const float*)d_in[6];
  const float* olab  = (const float*)d_in[7];
  const float* succ  = (const float*)d_in[8];
  const float* alab  = (const float*)d_in[9];
  const float* binv  = (const float*)d_in[10];
  const float* binw  = (const float*)d_in[11];
  const float* cpts  = (const float*)d_in[12];
  const float* scpts = (const float*)d_in[13];
  float* ws  = (float*)d_ws;
  float* out = (float*)d_out;

  k_prep<<<dim3(BN/256), dim3(256), 0, stream>>>(gdir, adirp, goff, ppts, bsh,
                                                 dlab, olab, succ, alab,
                                                 binv, binw, cpts, scpts, ws);
  k_pair<<<dim3(Nn/TCOLS, Nn/NCH, Bn), dim3(256), 0, stream>>>(succ, ws);
  k_red<<<dim3(Nn/256, Bn), dim3(256), 0, stream>>>(bsp, succ, ws);
  k_fin<<<1, 64, 0, stream>>>(ws, out);
}

// Round 6
// 126.773 us; speedup vs baseline: 1.1806x; 1.0977x over previous
//
#include <hip/hip_runtime.h>

#define Bn 4
#define Nn 2048
#define NBn 10
#define BN (Bn*Nn)
#define TCOLS 128     // gt columns per block (2 per lane, shared by all 4 waves)
#define NCH 64        // pred rows per block (16 per wave)
#define BIGM 1e32f

// ws layout in float (4-byte) units  (sym cloud eliminated: it's gt with pts 2<->3 swapped)
#define OFF_PRED 0
#define OFF_GT   (BN*16)
#define OFF_PN2  (2*BN*16)
#define OFF_GN2  (OFF_PN2 + BN)
#define OFF_BEST (OFF_GN2 + BN)      // u32 per (b,n): forward min dist (fp32 bits)
#define OFF_PK   (OFF_BEST + BN)     // u32 per (b,m): (dist&0xFFFFF000)|(mat<<11)|n
#define OFF_PART (OFF_PK + BN)       // 32 records x 8 floats: 0=dir 1=app 2=off 3=pos 4=bce 5=adds 6=g2p

__device__ inline float sp_(float x) {            // jax.nn.softplus, stable form
  return fmaxf(x, 0.0f) + log1pf(expf(-fabsf(x)));
}

// dot of wave-uniform pred row p[15] with lane's column quads (16th elem unused)
__device__ inline float dotp_(const float* p, const float4&b0,const float4&b1,const float4&b2,const float4&b3){
  float s0 = fmaf(p[3], b0.w, fmaf(p[2], b0.z, fmaf(p[1], b0.y, p[0]*b0.x)));
  float s1 = fmaf(p[7], b1.w, fmaf(p[6], b1.z, fmaf(p[5], b1.y, p[4]*b1.x)));
  float s2 = fmaf(p[11],b2.w, fmaf(p[10],b2.z, fmaf(p[9], b2.y, p[8]*b2.x)));
  float s3 = fmaf(p[14],b3.z, fmaf(p[13],b3.y, p[12]*b3.x));
  return (s0+s1)+(s2+s3);
}

__device__ inline float blockSum_(float v, float* red) {
  #pragma unroll
  for (int o = 32; o > 0; o >>= 1) v += __shfl_down(v, o, 64);
  __syncthreads();
  if ((threadIdx.x & 63) == 0) red[threadIdx.x >> 6] = v;
  __syncthreads();
  return red[0] + red[1] + red[2] + red[3];
}

// ---------- prep: frames, control points, norms, min-state init, cheap per-point
// loss partials. grid (BN/256) = 32, block 256.
__global__ __launch_bounds__(256) void k_prep(
    const float* __restrict__ gdir, const float* __restrict__ adirp,
    const float* __restrict__ goff, const float* __restrict__ ppts,
    const float* __restrict__ bsh,
    const float* __restrict__ dlab, const float* __restrict__ olab,
    const float* __restrict__ succ, const float* __restrict__ alab,
    const float* __restrict__ binv, const float* __restrict__ binw,
    const float* __restrict__ cpts, const float* __restrict__ scpts,
    float* __restrict__ ws)
{
  __shared__ float red[4];
  const int pb = blockIdx.x;
  const int idx = pb * 256 + threadIdx.x;

  const float gd0=gdir[idx*3+0],  gd1=gdir[idx*3+1],  gd2=gdir[idx*3+2];
  const float ad0=adirp[idx*3+0], ad1=adirp[idx*3+1], ad2=adirp[idx*3+2];
  const float dl0=dlab[idx*3+0],  dl1=dlab[idx*3+1],  dl2=dlab[idx*3+2];
  const float al0=alab[idx*3+0],  al1=alab[idx*3+1],  al2=alab[idx*3+2];
  const float pt0=ppts[idx*3+0],  pt1=ppts[idx*3+1],  pt2=ppts[idx*3+2];
  const float sc = succ[idx];

  // argmax (first occurrence, matches jnp.argmax)
  float bv = goff[idx*NBn]; int ap = 0;
  #pragma unroll
  for (int k = 1; k < NBn; k++) { float v = goff[idx*NBn+k]; if (v > bv) { bv = v; ap = k; } }
  float bg = olab[idx*NBn]; int ag = 0;
  #pragma unroll
  for (int k = 1; k < NBn; k++) { float v = olab[idx*NBn+k]; if (v > bg) { bg = v; ag = k; } }
  const float tp = binv[ap] * 0.5f;
  const float tg = binv[ag] * 0.5f;

  // frames: cross = cross(approach, base); t = pt + 0.5*thickness*base
  const float cp0 = ad1*gd2 - ad2*gd1, cp1 = ad2*gd0 - ad0*gd2, cp2 = ad0*gd1 - ad1*gd0;
  const float cg0 = al1*dl2 - al2*dl1, cg1 = al2*dl0 - al0*dl2, cg2 = al0*dl1 - al1*dl0;
  const float tpx = pt0 + tp*gd0, tpy = pt1 + tp*gd1, tpz = pt2 + tp*gd2;
  const float tgx = pt0 + tg*dl0, tgy = pt1 + tg*dl1, tgz = pt2 + tg*dl2;

  float pcp[15], gcp[15];
  float pn2 = 0.f, gn2 = 0.f;
  #pragma unroll
  for (int p = 0; p < 5; p++) {
    const float cx = cpts[p*3], cy = cpts[p*3+1], cz = cpts[p*3+2];
    float x, y, z;
    x = gd0*cx + cp0*cy + ad0*cz + tpx;
    y = gd1*cx + cp1*cy + ad1*cz + tpy;
    z = gd2*cx + cp2*cy + ad2*cz + tpz;
    pcp[p*3+0]=x; pcp[p*3+1]=y; pcp[p*3+2]=z;
    pn2 = fmaf(x,x, fmaf(y,y, fmaf(z,z, pn2)));
    x = dl0*cx + cg0*cy + al0*cz + tgx;
    y = dl1*cx + cg1*cy + al1*cz + tgy;
    z = dl2*cx + cg2*cy + al2*cz + tgz;
    gcp[p*3+0]=x; gcp[p*3+1]=y; gcp[p*3+2]=z;
    gn2 = fmaf(x,x, fmaf(y,y, fmaf(z,z, gn2)));
  }

  float4* pd = (float4*)(ws + OFF_PRED) + (size_t)idx*4;
  pd[0]=make_float4(pcp[0],pcp[1],pcp[2],pcp[3]);
  pd[1]=make_float4(pcp[4],pcp[5],pcp[6],pcp[7]);
  pd[2]=make_float4(pcp[8],pcp[9],pcp[10],pcp[11]);
  pd[3]=make_float4(pcp[12],pcp[13],pcp[14],0.f);
  float4* gdst = (float4*)(ws + OFF_GT) + (size_t)idx*4;
  gdst[0]=make_float4(gcp[0],gcp[1],gcp[2],gcp[3]);
  gdst[1]=make_float4(gcp[4],gcp[5],gcp[6],gcp[7]);
  gdst[2]=make_float4(gcp[8],gcp[9],gcp[10],gcp[11]);
  gdst[3]=make_float4(gcp[12],gcp[13],gcp[14],0.f);
  ws[OFF_PN2+idx] = pn2; ws[OFF_GN2+idx] = gn2;

  // per-idx min-state init (k_pair runs strictly after)
  ((unsigned*)ws)[OFF_BEST + idx] = 0x7F800000u;   // +inf
  ((unsigned*)ws)[OFF_PK   + idx] = 0xFFFFFFFFu;

  // ---- cheap per-point losses -> per-block partials ----
  const float cosd = 1.f - (dl0*gd0 + dl1*gd1 + dl2*gd2);
  const float proj = gd0*al0 + gd1*al1 + gd2*al2;
  const float o0 = al0 - proj*gd0, o1 = al1 - proj*gd1, o2 = al2 - proj*gd2;
  const float on = sqrtf(o0*o0 + o1*o1 + o2*o2);
  const float inv = 1.f / fmaxf(on, 1e-12f);
  const float cosa = 1.f - inv*(o0*ad0 + o1*ad1 + o2*ad2);

  float offv = 0.f;
  #pragma unroll
  for (int k = 0; k < NBn; k++) {
    const float x = goff[idx*NBn+k], lab = olab[idx*NBn+k];
    const float bce = lab * sp_(-x) + (1.f - lab) * sp_(x);
    offv = fmaf(binw[k], bce, offv);
  }
  offv *= (1.0f / NBn);
  const float sb = bsh[idx];
  const float sbce = sc * sp_(-sb) + (1.f - sc) * sp_(sb);

  float* part = ws + OFF_PART + (size_t)pb*8;
  float t;
  t = blockSum_(cosd*sc, red); if (threadIdx.x == 0) part[0] = t;
  t = blockSum_(cosa*sc, red); if (threadIdx.x == 0) part[1] = t;
  t = blockSum_(offv*sc, red); if (threadIdx.x == 0) part[2] = t;
  t = blockSum_(sc, red);      if (threadIdx.x == 0) part[3] = t;
  t = blockSum_(sbce, red);    if (threadIdx.x == 0) part[4] = t;
}

// ---------- single-pass pairwise kernel. grid (Nn/TCOLS, Nn/NCH, Bn) = (16,32,4), block 256.
// Each lane owns 2 gt columns in registers. Sym distances via the permutation identity:
//   sym_cp = gt_cp with point rows 2<->3 swapped, sn2 == gn2,
//   dot_sym = dot_gt + (p[6..8]-p[9..11]) . (g[9..11]-g[6..8]).
// Loop body is PURE VALU (no cross-lane ops): forward mins land in f[16] (static idx),
// one batched 6-step butterfly at the end (16 independent chains, latency pipelined).
__global__ __launch_bounds__(256) void k_pair(const float* __restrict__ succ,
                                              float* __restrict__ ws) {
  __shared__ unsigned bkey[TCOLS];
  const int tile = blockIdx.x * TCOLS, b = blockIdx.z;
  const int bN = b * Nn;
  const int tid = threadIdx.x;
  const int lane = tid & 63;
  const int wid = __builtin_amdgcn_readfirstlane(tid >> 6);

  if (tid < TCOLS) bkey[tid] = 0xFFFFFFFFu;

  // lane's two columns
  const int r0 = bN + tile + lane;
  const int r1 = r0 + 64;
  const float4* G = (const float4*)(ws + OFF_GT);
  const float4 g00=G[(size_t)r0*4+0], g01=G[(size_t)r0*4+1], g02=G[(size_t)r0*4+2], g03=G[(size_t)r0*4+3];
  const float4 g10=G[(size_t)r1*4+0], g11=G[(size_t)r1*4+1], g12=G[(size_t)r1*4+2], g13=G[(size_t)r1*4+3];
  const float gn0 = ws[OFF_GN2+r0], gn1 = ws[OFF_GN2+r1];
  const float bias0 = (succ[r0] != 0.f) ? 0.f : BIGM;
  const float bias1 = (succ[r1] != 0.f) ? 0.f : BIGM;
  // sym-delta fragments: g[9..11] - g[6..8]  (float idx 9,10,11 = g02.y,z,w ; 6,7,8 = g01.z,w,g02.x)
  const float e0x = g02.y - g01.z, e0y = g02.z - g01.w, e0z = g02.w - g02.x;
  const float e1x = g12.y - g11.z, e1y = g12.z - g11.w, e1z = g12.w - g12.x;

  unsigned k0 = 0xFFFFFFFFu, k1 = 0xFFFFFFFFu;
  float f[16];
  __syncthreads();

  const int nbase = blockIdx.y * NCH + wid * 16;
  const float* prow = ws + OFF_PRED + (size_t)(bN + nbase)*16;
  const float* pn2p = ws + OFF_PN2 + bN + nbase;

  #pragma unroll
  for (int j = 0; j < 16; j++) {
    float p[15];
    #pragma unroll
    for (int q = 0; q < 15; q++) p[q] = prow[j*16 + q];        // wave-uniform (scalar) loads
    const float pn2 = pn2p[j];
    const float pd0 = p[6]-p[9], pd1 = p[7]-p[10], pd2 = p[8]-p[11];

    const float dot0 = dotp_(p, g00,g01,g02,g03);
    const float del0 = fmaf(pd0, e0x, fmaf(pd1, e0y, pd2*e0z));
    const float q10  = fmaf(-2.f, dot0, pn2 + gn0);
    const float d10  = fmaxf(q10, 0.f);
    const float d20  = fmaxf(fmaf(-2.f, del0, q10), 0.f);

    const float dot1 = dotp_(p, g10,g11,g12,g13);
    const float del1 = fmaf(pd0, e1x, fmaf(pd1, e1y, pd2*e1z));
    const float q11  = fmaf(-2.f, dot1, pn2 + gn1);
    const float d11  = fmaxf(q11, 0.f);
    const float d21  = fmaxf(fmaf(-2.f, del1, q11), 0.f);

    // backward packed keys: (dist&0xFFFFF000)|(mat<<11)|n — u32 min is lexicographic
    // (d, mat, n): d-tie -> mat0 (= reference i1-on-tie), then first n.
    const unsigned nl = (unsigned)(nbase + j), nh = nl | 0x800u;
    k0 = min(k0, min((__float_as_uint(d10) & 0xFFFFF000u) | nl,
                     (__float_as_uint(d20) & 0xFFFFF000u) | nh));
    k1 = min(k1, min((__float_as_uint(d11) & 0xFFFFF000u) | nl,
                     (__float_as_uint(d21) & 0xFFFFF000u) | nh));

    // forward per-lane min (mask folded as bias); cross-lane deferred to tail
    f[j] = fminf(fminf(d10, d20) + bias0, fminf(d11, d21) + bias1);
  }

  // batched butterfly: 16 independent min-chains, 6 steps
  #pragma unroll
  for (int o = 1; o < 64; o <<= 1) {
    #pragma unroll
    for (int j = 0; j < 16; j++) f[j] = fminf(f[j], __shfl_xor(f[j], o, 64));
  }
  if (lane == 0) {
    #pragma unroll
    for (int j = 0; j < 16; j++)
      atomicMin((unsigned*)ws + OFF_BEST + bN + nbase + j, __float_as_uint(f[j]));
  }

  // merge the 4 waves' backward keys (same columns, disjoint n) then one global atomic/col
  atomicMin(&bkey[lane], k0);
  atomicMin(&bkey[64 + lane], k1);
  __syncthreads();
  if (tid < TCOLS)
    atomicMin((unsigned*)ws + OFF_PK + bN + tile + tid, bkey[tid]);
}

// ---------- reduce: adds/g2p per-block partials. grid (Nn/256, Bn) = (8,4), block 256.
__global__ __launch_bounds__(256) void k_red(const float* __restrict__ bsp,
                                             const float* __restrict__ succ,
                                             float* __restrict__ ws) {
  __shared__ float red[4];
  const int b = blockIdx.y, nt = blockIdx.x;
  const int idx = b*Nn + nt*256 + threadIdx.x;

  const float best = __uint_as_float(((const unsigned*)ws)[OFF_BEST + idx]);
  const float adds = (best < 1e30f) ? bsp[idx] * sqrtf(best) : 0.f;  // >=1e30 <=> no positives -> gate 0

  const unsigned key = ((const unsigned*)ws)[OFF_PK + idx];
  const float d = __uint_as_float(key & 0xFFFFF000u);
  const int  id = (int)(key & 0x7FFu);
  const float g2p = bsp[b*Nn + id] * d * succ[idx];

  float* part = ws + OFF_PART + (size_t)(b*8 + nt)*8;
  float t;
  t = blockSum_(adds, red); if (threadIdx.x == 0) part[5] = t;
  t = blockSum_(g2p, red);  if (threadIdx.x == 0) part[6] = t;
}

// ---------- finalize: 1 block, 64 threads, wave-only reduction of 32x7 partials
__global__ __launch_bounds__(64) void k_fin(const float* __restrict__ ws, float* __restrict__ out) {
  const int t = threadIdx.x;
  float v[7];
  #pragma unroll
  for (int c = 0; c < 7; c++) v[c] = (t < 32) ? ws[OFF_PART + t*8 + c] : 0.f;
  #pragma unroll
  for (int o = 1; o < 8; o <<= 1) {
    #pragma unroll
    for (int c = 0; c < 7; c++) v[c] += __shfl_xor(v[c], o, 64);
  }
  // each 8-lane group (t<32) now holds per-b sums (b = t>>3)
  const float pos = fmaxf(v[3], 1.f);
  float vb   = (v[0] + v[1] + v[2] + v[6]) / pos;   // dir + app + off + g2p, per-b normalized
  float bce  = v[4];
  float adds = v[5];
  #pragma unroll
  for (int o = 8; o < 32; o <<= 1) {
    vb   += __shfl_xor(vb,   o, 64);
    bce  += __shfl_xor(bce,  o, 64);
    adds += __shfl_xor(adds, o, 64);
  }
  if (t == 0)
    out[0] = vb * 0.25f + bce * (1.f/BN) + 10.f * adds * (1.f/BN);
}

extern "C" void kernel_launch(void* const* d_in, const int* in_sizes, int n_in,
                              void* d_out, int out_size, void* d_ws, size_t ws_size,
                              hipStream_t stream) {
  const float* gdir  = (const float*)d_in[0];
  const float* adirp = (const float*)d_in[1];
  const float* goff  = (const float*)d_in[2];
  const float* ppts  = (const float*)d_in[3];
  const float* bsp   = (const float*)d_in[4];
  const float* bsh   = (const float*)d_in[5];
  const float* dlab  = (const float*)d_in[6];
  const float* olab  = (const float*)d_in[7];
  const float* succ  = (const float*)d_in[8];
  const float* alab  = (const float*)d_in[9];
  const float* binv  = (const float*)d_in[10];
  const float* binw  = (const float*)d_in[11];
  const float* cpts  = (const float*)d_in[12];
  const float* scpts = (const float*)d_in[13];
  float* ws  = (float*)d_ws;
  float* out = (float*)d_out;
  (void)scpts;

  k_prep<<<dim3(BN/256), dim3(256), 0, stream>>>(gdir, adirp, goff, ppts, bsh,
                                                 dlab, olab, succ, alab,
                                                 binv, binw, cpts, scpts, ws);
  k_pair<<<dim3(Nn/TCOLS, Nn/NCH, Bn), dim3(256), 0, stream>>>(succ, ws);
  k_red<<<dim3(Nn/256, Bn), dim3(256), 0, stream>>>(bsp, succ, ws);
  k_fin<<<1, 64, 0, stream>>>(ws, out);
}

// Round 7
// 124.630 us; speedup vs baseline: 1.2009x; 1.0172x over previous
//
#include <hip/hip_runtime.h>

#define Bn 4
#define Nn 2048
#define NBn 10
#define BN (Bn*Nn)
#define TCOLS 128     // gt columns per block (2 per lane, shared by all 4 waves)
#define NCH 64        // pred rows per block (16 per wave)
#define BIGM 1e32f

// ws layout in float (4-byte) units  (sym cloud eliminated: it's gt with pts 2<->3 swapped)
#define OFF_PRED 0
#define OFF_GT   (BN*16)
#define OFF_PN2  (2*BN*16)
#define OFF_GN2  (OFF_PN2 + BN)
#define OFF_BEST (OFF_GN2 + BN)      // u32 per (b,n): forward min dist (fp32 bits)
#define OFF_PK   (OFF_BEST + BN)     // u32 per (b,m): (dist&0xFFFFF000)|(mat<<11)|n
#define OFF_PART (OFF_PK + BN)       // 32 records x 8 floats: 0=dir 1=app 2=off 3=pos 4=bce 5=adds 6=g2p

__device__ inline float sp_(float x) {            // jax.nn.softplus, stable form
  return fmaxf(x, 0.0f) + log1pf(expf(-fabsf(x)));
}

__device__ inline float blockSum_(float v, float* red) {
  #pragma unroll
  for (int o = 32; o > 0; o >>= 1) v += __shfl_down(v, o, 64);
  __syncthreads();
  if ((threadIdx.x & 63) == 0) red[threadIdx.x >> 6] = v;
  __syncthreads();
  return red[0] + red[1] + red[2] + red[3];
}

// ---------- prep: frames, control points, norms, min-state init, cheap per-point
// loss partials. grid (BN/256) = 32, block 256.
__global__ __launch_bounds__(256) void k_prep(
    const float* __restrict__ gdir, const float* __restrict__ adirp,
    const float* __restrict__ goff, const float* __restrict__ ppts,
    const float* __restrict__ bsh,
    const float* __restrict__ dlab, const float* __restrict__ olab,
    const float* __restrict__ succ, const float* __restrict__ alab,
    const float* __restrict__ binv, const float* __restrict__ binw,
    const float* __restrict__ cpts, const float* __restrict__ scpts,
    float* __restrict__ ws)
{
  __shared__ float red[4];
  const int pb = blockIdx.x;
  const int idx = pb * 256 + threadIdx.x;

  const float gd0=gdir[idx*3+0],  gd1=gdir[idx*3+1],  gd2=gdir[idx*3+2];
  const float ad0=adirp[idx*3+0], ad1=adirp[idx*3+1], ad2=adirp[idx*3+2];
  const float dl0=dlab[idx*3+0],  dl1=dlab[idx*3+1],  dl2=dlab[idx*3+2];
  const float al0=alab[idx*3+0],  al1=alab[idx*3+1],  al2=alab[idx*3+2];
  const float pt0=ppts[idx*3+0],  pt1=ppts[idx*3+1],  pt2=ppts[idx*3+2];
  const float sc = succ[idx];

  // argmax (first occurrence, matches jnp.argmax)
  float bv = goff[idx*NBn]; int ap = 0;
  #pragma unroll
  for (int k = 1; k < NBn; k++) { float v = goff[idx*NBn+k]; if (v > bv) { bv = v; ap = k; } }
  float bg = olab[idx*NBn]; int ag = 0;
  #pragma unroll
  for (int k = 1; k < NBn; k++) { float v = olab[idx*NBn+k]; if (v > bg) { bg = v; ag = k; } }
  const float tp = binv[ap] * 0.5f;
  const float tg = binv[ag] * 0.5f;

  // frames: cross = cross(approach, base); t = pt + 0.5*thickness*base
  const float cp0 = ad1*gd2 - ad2*gd1, cp1 = ad2*gd0 - ad0*gd2, cp2 = ad0*gd1 - ad1*gd0;
  const float cg0 = al1*dl2 - al2*dl1, cg1 = al2*dl0 - al0*dl2, cg2 = al0*dl1 - al1*dl0;
  const float tpx = pt0 + tp*gd0, tpy = pt1 + tp*gd1, tpz = pt2 + tp*gd2;
  const float tgx = pt0 + tg*dl0, tgy = pt1 + tg*dl1, tgz = pt2 + tg*dl2;

  float pcp[15], gcp[15];
  float pn2 = 0.f, gn2 = 0.f;
  #pragma unroll
  for (int p = 0; p < 5; p++) {
    const float cx = cpts[p*3], cy = cpts[p*3+1], cz = cpts[p*3+2];
    float x, y, z;
    x = gd0*cx + cp0*cy + ad0*cz + tpx;
    y = gd1*cx + cp1*cy + ad1*cz + tpy;
    z = gd2*cx + cp2*cy + ad2*cz + tpz;
    pcp[p*3+0]=x; pcp[p*3+1]=y; pcp[p*3+2]=z;
    pn2 = fmaf(x,x, fmaf(y,y, fmaf(z,z, pn2)));
    x = dl0*cx + cg0*cy + al0*cz + tgx;
    y = dl1*cx + cg1*cy + al1*cz + tgy;
    z = dl2*cx + cg2*cy + al2*cz + tgz;
    gcp[p*3+0]=x; gcp[p*3+1]=y; gcp[p*3+2]=z;
    gn2 = fmaf(x,x, fmaf(y,y, fmaf(z,z, gn2)));
  }

  float4* pd = (float4*)(ws + OFF_PRED) + (size_t)idx*4;
  pd[0]=make_float4(pcp[0],pcp[1],pcp[2],pcp[3]);
  pd[1]=make_float4(pcp[4],pcp[5],pcp[6],pcp[7]);
  pd[2]=make_float4(pcp[8],pcp[9],pcp[10],pcp[11]);
  pd[3]=make_float4(pcp[12],pcp[13],pcp[14],0.f);
  float4* gdst = (float4*)(ws + OFF_GT) + (size_t)idx*4;
  gdst[0]=make_float4(gcp[0],gcp[1],gcp[2],gcp[3]);
  gdst[1]=make_float4(gcp[4],gcp[5],gcp[6],gcp[7]);
  gdst[2]=make_float4(gcp[8],gcp[9],gcp[10],gcp[11]);
  gdst[3]=make_float4(gcp[12],gcp[13],gcp[14],0.f);
  ws[OFF_PN2+idx] = pn2; ws[OFF_GN2+idx] = gn2;

  // per-idx min-state init (k_pair runs strictly after)
  ((unsigned*)ws)[OFF_BEST + idx] = 0x7F800000u;   // +inf
  ((unsigned*)ws)[OFF_PK   + idx] = 0xFFFFFFFFu;

  // ---- cheap per-point losses -> per-block partials ----
  const float cosd = 1.f - (dl0*gd0 + dl1*gd1 + dl2*gd2);
  const float proj = gd0*al0 + gd1*al1 + gd2*al2;
  const float o0 = al0 - proj*gd0, o1 = al1 - proj*gd1, o2 = al2 - proj*gd2;
  const float on = sqrtf(o0*o0 + o1*o1 + o2*o2);
  const float inv = 1.f / fmaxf(on, 1e-12f);
  const float cosa = 1.f - inv*(o0*ad0 + o1*ad1 + o2*ad2);

  float offv = 0.f;
  #pragma unroll
  for (int k = 0; k < NBn; k++) {
    const float x = goff[idx*NBn+k], lab = olab[idx*NBn+k];
    const float bce = lab * sp_(-x) + (1.f - lab) * sp_(x);
    offv = fmaf(binw[k], bce, offv);
  }
  offv *= (1.0f / NBn);
  const float sb = bsh[idx];
  const float sbce = sc * sp_(-sb) + (1.f - sc) * sp_(sb);

  float* part = ws + OFF_PART + (size_t)pb*8;
  float t;
  t = blockSum_(cosd*sc, red); if (threadIdx.x == 0) part[0] = t;
  t = blockSum_(cosa*sc, red); if (threadIdx.x == 0) part[1] = t;
  t = blockSum_(offv*sc, red); if (threadIdx.x == 0) part[2] = t;
  t = blockSum_(sc, red);      if (threadIdx.x == 0) part[3] = t;
  t = blockSum_(sbce, red);    if (threadIdx.x == 0) part[4] = t;
}

// ---------- single-pass pairwise kernel. grid (Nn/TCOLS, Nn/NCH, Bn) = (16,32,4), block 256.
// Each lane owns 2 gt columns in registers. Sym distances via the permutation identity
// (sym = gt with pts 2<->3 swapped): dot_sym = dot_gt + (p[6..8]-p[9..11]).(g[9..11]-g[6..8]).
// Pred rows are staged in LDS (4.4 KB) and read per-j at a wave-uniform address
// (broadcast ds_read_b128, FIFO lgkmcnt, prefetchable) — replaces the s_load serial chain.
__global__ __launch_bounds__(256, 4) void k_pair(const float* __restrict__ succ,
                                                 float* __restrict__ ws) {
  __shared__ float pls[NCH*16];       // 64 pred rows x 16 floats
  __shared__ float pn2s[NCH];
  __shared__ unsigned bkey[TCOLS];
  const int tile = blockIdx.x * TCOLS, b = blockIdx.z;
  const int bN = b * Nn;
  const int ny0 = blockIdx.y * NCH;
  const int tid = threadIdx.x;
  const int lane = tid & 63;
  const int wid = __builtin_amdgcn_readfirstlane(tid >> 6);

  // stage pred rows: 256 threads x 1 float4 = 64 rows x 16 floats
  {
    const int row = tid >> 2, q = tid & 3;
    ((float4*)pls)[tid] = ((const float4*)(ws + OFF_PRED))[(size_t)(bN + ny0 + row)*4 + q];
    if (tid < NCH) pn2s[tid] = ws[OFF_PN2 + bN + ny0 + tid];
    if (tid < TCOLS) bkey[tid] = 0xFFFFFFFFu;
  }

  // lane's two columns
  const int r0 = bN + tile + lane;
  const int r1 = r0 + 64;
  const float4* G = (const float4*)(ws + OFF_GT);
  const float4 g00=G[(size_t)r0*4+0], g01=G[(size_t)r0*4+1], g02=G[(size_t)r0*4+2], g03=G[(size_t)r0*4+3];
  const float4 g10=G[(size_t)r1*4+0], g11=G[(size_t)r1*4+1], g12=G[(size_t)r1*4+2], g13=G[(size_t)r1*4+3];
  const float gn0 = ws[OFF_GN2+r0], gn1 = ws[OFF_GN2+r1];
  const float bias0 = (succ[r0] != 0.f) ? 0.f : BIGM;
  const float bias1 = (succ[r1] != 0.f) ? 0.f : BIGM;
  // sym-delta fragments: g[9..11] - g[6..8]
  const float e0x = g02.y - g01.z, e0y = g02.z - g01.w, e0z = g02.w - g02.x;
  const float e1x = g12.y - g11.z, e1y = g12.z - g11.w, e1z = g12.w - g12.x;

  unsigned k0 = 0xFFFFFFFFu, k1 = 0xFFFFFFFFu;
  float f[16];
  __syncthreads();

  const float4* PL = (const float4*)pls + (size_t)wid*16*4;   // this wave's 16 rows

  #pragma unroll
  for (int j = 0; j < 16; j++) {
    const float4 p0 = PL[j*4+0], p1 = PL[j*4+1], p2 = PL[j*4+2], p3 = PL[j*4+3];
    const float pn2 = pn2s[wid*16 + j];
    const float pd0 = p1.z - p2.y, pd1 = p1.w - p2.z, pd2 = p2.x - p2.w;

    float dot0, dot1, s;
    s    = fmaf(p0.w, g00.w, fmaf(p0.z, g00.z, fmaf(p0.y, g00.y, p0.x*g00.x)));
    s    = fmaf(p1.w, g01.w, fmaf(p1.z, g01.z, fmaf(p1.y, g01.y, fmaf(p1.x, g01.x, s))));
    s    = fmaf(p2.w, g02.w, fmaf(p2.z, g02.z, fmaf(p2.y, g02.y, fmaf(p2.x, g02.x, s))));
    dot0 = fmaf(p3.z, g03.z, fmaf(p3.y, g03.y, fmaf(p3.x, g03.x, s)));
    s    = fmaf(p0.w, g10.w, fmaf(p0.z, g10.z, fmaf(p0.y, g10.y, p0.x*g10.x)));
    s    = fmaf(p1.w, g11.w, fmaf(p1.z, g11.z, fmaf(p1.y, g11.y, fmaf(p1.x, g11.x, s))));
    s    = fmaf(p2.w, g12.w, fmaf(p2.z, g12.z, fmaf(p2.y, g12.y, fmaf(p2.x, g12.x, s))));
    dot1 = fmaf(p3.z, g13.z, fmaf(p3.y, g13.y, fmaf(p3.x, g13.x, s)));

    const float del0 = fmaf(pd0, e0x, fmaf(pd1, e0y, pd2*e0z));
    const float q10  = fmaf(-2.f, dot0, pn2 + gn0);
    const float d10  = fmaxf(q10, 0.f);
    const float d20  = fmaxf(fmaf(-2.f, del0, q10), 0.f);

    const float del1 = fmaf(pd0, e1x, fmaf(pd1, e1y, pd2*e1z));
    const float q11  = fmaf(-2.f, dot1, pn2 + gn1);
    const float d11  = fmaxf(q11, 0.f);
    const float d21  = fmaxf(fmaf(-2.f, del1, q11), 0.f);

    // backward packed keys: (dist&0xFFFFF000)|(mat<<11)|n — u32 min is lexicographic
    // (d, mat, n): d-tie -> mat0 (= reference i1-on-tie), then first n.
    const unsigned nl = (unsigned)(ny0 + wid*16 + j), nh = nl | 0x800u;
    k0 = min(k0, min((__float_as_uint(d10) & 0xFFFFF000u) | nl,
                     (__float_as_uint(d20) & 0xFFFFF000u) | nh));
    k1 = min(k1, min((__float_as_uint(d11) & 0xFFFFF000u) | nl,
                     (__float_as_uint(d21) & 0xFFFFF000u) | nh));

    // forward per-lane min (mask folded as bias); cross-lane deferred to tail
    f[j] = fminf(fminf(d10, d20) + bias0, fminf(d11, d21) + bias1);
  }

  // batched butterfly: 16 independent min-chains, 6 steps (latency pipelined)
  #pragma unroll
  for (int o = 1; o < 64; o <<= 1) {
    #pragma unroll
    for (int j = 0; j < 16; j++) f[j] = fminf(f[j], __shfl_xor(f[j], o, 64));
  }
  if (lane == 0) {
    #pragma unroll
    for (int j = 0; j < 16; j++)
      atomicMin((unsigned*)ws + OFF_BEST + bN + ny0 + wid*16 + j, __float_as_uint(f[j]));
  }

  // merge the 4 waves' backward keys (same columns, disjoint n) then one global atomic/col
  atomicMin(&bkey[lane], k0);
  atomicMin(&bkey[64 + lane], k1);
  __syncthreads();
  if (tid < TCOLS)
    atomicMin((unsigned*)ws + OFF_PK + bN + tile + tid, bkey[tid]);
}

// ---------- reduce: adds/g2p per-block partials. grid (Nn/256, Bn) = (8,4), block 256.
__global__ __launch_bounds__(256) void k_red(const float* __restrict__ bsp,
                                             const float* __restrict__ succ,
                                             float* __restrict__ ws) {
  __shared__ float red[4];
  const int b = blockIdx.y, nt = blockIdx.x;
  const int idx = b*Nn + nt*256 + threadIdx.x;

  const float best = __uint_as_float(((const unsigned*)ws)[OFF_BEST + idx]);
  const float adds = (best < 1e30f) ? bsp[idx] * sqrtf(best) : 0.f;  // >=1e30 <=> no positives -> gate 0

  const unsigned key = ((const unsigned*)ws)[OFF_PK + idx];
  const float d = __uint_as_float(key & 0xFFFFF000u);
  const int  id = (int)(key & 0x7FFu);
  const float g2p = bsp[b*Nn + id] * d * succ[idx];

  float* part = ws + OFF_PART + (size_t)(b*8 + nt)*8;
  float t;
  t = blockSum_(adds, red); if (threadIdx.x == 0) part[5] = t;
  t = blockSum_(g2p, red);  if (threadIdx.x == 0) part[6] = t;
}

// ---------- finalize: 1 block, 64 threads, wave-only reduction of 32x7 partials
__global__ __launch_bounds__(64) void k_fin(const float* __restrict__ ws, float* __restrict__ out) {
  const int t = threadIdx.x;
  float v[7];
  #pragma unroll
  for (int c = 0; c < 7; c++) v[c] = (t < 32) ? ws[OFF_PART + t*8 + c] : 0.f;
  #pragma unroll
  for (int o = 1; o < 8; o <<= 1) {
    #pragma unroll
    for (int c = 0; c < 7; c++) v[c] += __shfl_xor(v[c], o, 64);
  }
  // each 8-lane group (t<32) now holds per-b sums (b = t>>3)
  const float pos = fmaxf(v[3], 1.f);
  float vb   = (v[0] + v[1] + v[2] + v[6]) / pos;   // dir + app + off + g2p, per-b normalized
  float bce  = v[4];
  float adds = v[5];
  #pragma unroll
  for (int o = 8; o < 32; o <<= 1) {
    vb   += __shfl_xor(vb,   o, 64);
    bce  += __shfl_xor(bce,  o, 64);
    adds += __shfl_xor(adds, o, 64);
  }
  if (t == 0)
    out[0] = vb * 0.25f + bce * (1.f/BN) + 10.f * adds * (1.f/BN);
}

extern "C" void kernel_launch(void* const* d_in, const int* in_sizes, int n_in,
                              void* d_out, int out_size, void* d_ws, size_t ws_size,
                              hipStream_t stream) {
  const float* gdir  = (const float*)d_in[0];
  const float* adirp = (const float*)d_in[1];
  const float* goff  = (const float*)d_in[2];
  const float* ppts  = (const float*)d_in[3];
  const float* bsp   = (const float*)d_in[4];
  const float* bsh   = (const float*)d_in[5];
  const float* dlab  = (const float*)d_in[6];
  const float* olab  = (const float*)d_in[7];
  const float* succ  = (const float*)d_in[8];
  const float* alab  = (const float*)d_in[9];
  const float* binv  = (const float*)d_in[10];
  const float* binw  = (const float*)d_in[11];
  const float* cpts  = (const float*)d_in[12];
  const float* scpts = (const float*)d_in[13];
  float* ws  = (float*)d_ws;
  float* out = (float*)d_out;
  (void)scpts;

  k_prep<<<dim3(BN/256), dim3(256), 0, stream>>>(gdir, adirp, goff, ppts, bsh,
                                                 dlab, olab, succ, alab,
                                                 binv, binw, cpts, scpts, ws);
  k_pair<<<dim3(Nn/TCOLS, Nn/NCH, Bn), dim3(256), 0, stream>>>(succ, ws);
  k_red<<<dim3(Nn/256, Bn), dim3(256), 0, stream>>>(bsp, succ, ws);
  k_fin<<<1, 64, 0, stream>>>(ws, out);
}